// Round 5
// baseline (342.496 us; speedup 1.0000x reference)
//
#include <hip/hip_runtime.h>
#include <math.h>

#define T_LEN 200000
#define DIM   512
#define HID   512
#define KTOP  64
#define NBIN  4096
#define CAPB  4096
#define GRID  2048
#define NB_GRU 64
#define NB_ALPHA (GRID - NB_GRU)          // 1984
#define S_STRIDE (NB_ALPHA * 4)           // 7936 wave slots

// workspace layout (bytes)
#define OFF_ALPHA 0u            // 800000
#define OFF_HIST  800000u       // NBIN*4 = 16384
#define OFF_CNT   816384u       // 4 (zeroed together with hist)
#define OFF_CANDK 816400u       // CAPB*4
#define OFF_CANDI 832784u       // CAPB*4

__device__ __forceinline__ unsigned monokey(float f) {
    unsigned u = __float_as_uint(f);
    return (u & 0x80000000u) ? ~u : (u | 0x80000000u);
}
__device__ __forceinline__ float unmonokey(unsigned k) {
    return __uint_as_float((k & 0x80000000u) ? (k & 0x7fffffffu) : ~k);
}
__device__ __forceinline__ float dot8(float4 a0, float4 a1, float4 f0, float4 f1) {
    return a0.x*f0.x + a0.y*f0.y + a0.z*f0.z + a0.w*f0.w
         + a1.x*f1.x + a1.y*f1.y + a1.z*f1.z + a1.w*f1.w;
}

__global__ __launch_bounds__(256, 8)
void k_all(const float* __restrict__ fs, const float* __restrict__ fea,
           const float* __restrict__ h, const float* __restrict__ hs,
           const float* __restrict__ w_ih, const float* __restrict__ w_hh,
           const float* __restrict__ b_ih, const float* __restrict__ b_hh,
           const float* __restrict__ Wout, const float* __restrict__ bout,
           float* __restrict__ alpha, unsigned* __restrict__ ghist,
           unsigned* __restrict__ counter,
           unsigned* __restrict__ candk, unsigned* __restrict__ candi,
           float* __restrict__ out) {
    __shared__ unsigned lhist[NBIN];       // 16 KB; reused as hist copy in epilogue
    __shared__ unsigned s_last;
    __shared__ unsigned s_bucket, s_rank, s_kth, s_ntop, s_ncand;
    __shared__ float    s_val[96];
    __shared__ int      s_sidx[96];
    __shared__ float    s_wgt[KTOP];
    __shared__ float    s_attn[HID];
    __shared__ float    s_logit[8];

    int tid = threadIdx.x;
    int b   = blockIdx.x;
    int lane = tid & 63;
    int wv   = tid >> 6;

    if (b < NB_GRU) {
        // ---------------- GRU: 8 hidden units per block ----------------
        int tx = tid & 31, ty = tid >> 5;
        int j  = b * 8 + ty;
        const float4* f4  = (const float4*)fea;
        const float4* h4  = (const float4*)h;
        const float4* wi4 = (const float4*)w_ih;
        const float4* wh4 = (const float4*)w_hh;
        int r0 = j, r1 = HID + j, r2 = 2 * HID + j;
        float gir = 0, giz = 0, gin = 0, ghr = 0, ghz = 0, ghn = 0;
        #pragma unroll
        for (int it = 0; it < 4; ++it) {
            int c = tx + it * 32;
            float4 x = f4[c], hh = h4[c];
            float4 w;
            w = wi4[(size_t)r0 * 128 + c]; gir += w.x*x.x + w.y*x.y + w.z*x.z + w.w*x.w;
            w = wi4[(size_t)r1 * 128 + c]; giz += w.x*x.x + w.y*x.y + w.z*x.z + w.w*x.w;
            w = wi4[(size_t)r2 * 128 + c]; gin += w.x*x.x + w.y*x.y + w.z*x.z + w.w*x.w;
            w = wh4[(size_t)r0 * 128 + c]; ghr += w.x*hh.x + w.y*hh.y + w.z*hh.z + w.w*hh.w;
            w = wh4[(size_t)r1 * 128 + c]; ghz += w.x*hh.x + w.y*hh.y + w.z*hh.z + w.w*hh.w;
            w = wh4[(size_t)r2 * 128 + c]; ghn += w.x*hh.x + w.y*hh.y + w.z*hh.z + w.w*hh.w;
        }
        #pragma unroll
        for (int d = 16; d; d >>= 1) {
            gir += __shfl_xor(gir, d, 64);
            giz += __shfl_xor(giz, d, 64);
            gin += __shfl_xor(gin, d, 64);
            ghr += __shfl_xor(ghr, d, 64);
            ghz += __shfl_xor(ghz, d, 64);
            ghn += __shfl_xor(ghn, d, 64);
        }
        if (tx == 0) {
            float r = 1.f / (1.f + expf(-(gir + b_ih[r0] + ghr + b_hh[r0])));
            float z = 1.f / (1.f + expf(-(giz + b_ih[r1] + ghz + b_hh[r1])));
            float n = tanhf(gin + b_ih[r2] + r * (ghn + b_hh[r2]));
            out[5 + j] = (1.f - z) * n + z * h[j];
        }
    } else {
        // ---------------- alpha matvec + 4096-bin histogram ----------------
        #pragma unroll
        for (int i = 0; i < NBIN / 256; ++i) lhist[tid + i * 256] = 0u;
        __syncthreads();

        const float4* fs4  = (const float4*)fs;
        const float4* fea4 = (const float4*)fea;
        float4 f0 = fea4[lane];
        float4 f1 = fea4[64 + lane];
        int base = (b - NB_GRU) * 4 + wv;
        for (int r = base; r < T_LEN; r += 4 * S_STRIDE) {
            int r1 = r + S_STRIDE, r2 = r + 2 * S_STRIDE, r3 = r + 3 * S_STRIDE;
            bool g1 = r1 < T_LEN, g2 = r2 < T_LEN, g3 = r3 < T_LEN;
            const float4* p0 = fs4 + (size_t)r * 128;
            float4 a0 = p0[lane], a1 = p0[64 + lane];
            float4 b0 = {0,0,0,0}, b1 = b0, c0 = b0, c1 = b0, d0 = b0, d1 = b0;
            if (g1) { const float4* p = fs4 + (size_t)r1 * 128; b0 = p[lane]; b1 = p[64 + lane]; }
            if (g2) { const float4* p = fs4 + (size_t)r2 * 128; c0 = p[lane]; c1 = p[64 + lane]; }
            if (g3) { const float4* p = fs4 + (size_t)r3 * 128; d0 = p[lane]; d1 = p[64 + lane]; }
            float s0 = dot8(a0, a1, f0, f1);
            float s1 = dot8(b0, b1, f0, f1);
            float s2 = dot8(c0, c1, f0, f1);
            float s3 = dot8(d0, d1, f0, f1);
            #pragma unroll
            for (int m = 32; m; m >>= 1) {
                s0 += __shfl_xor(s0, m, 64);
                s1 += __shfl_xor(s1, m, 64);
                s2 += __shfl_xor(s2, m, 64);
                s3 += __shfl_xor(s3, m, 64);
            }
            if (lane == 0) {
                alpha[r] = s0; atomicAdd(&lhist[monokey(s0) >> 20], 1u);
                if (g1) { alpha[r1] = s1; atomicAdd(&lhist[monokey(s1) >> 20], 1u); }
                if (g2) { alpha[r2] = s2; atomicAdd(&lhist[monokey(s2) >> 20], 1u); }
                if (g3) { alpha[r3] = s3; atomicAdd(&lhist[monokey(s3) >> 20], 1u); }
            }
        }
        __syncthreads();
        #pragma unroll
        for (int i = 0; i < NBIN / 256; ++i) {
            unsigned c = lhist[tid + i * 256];
            if (c) atomicAdd(&ghist[tid + i * 256], c);
        }
    }

    // ---------------- last-block handoff ----------------
    __syncthreads();
    if (tid == 0) {
        __threadfence();
        s_last = (atomicAdd(counter, 1u) == GRID - 1) ? 1u : 0u;
    }
    __syncthreads();
    if (!s_last) return;
    __threadfence();

    // ---------------- epilogue (single block, 256 threads) ----------------
    for (int i = tid; i < NBIN; i += 256) lhist[i] = ghist[i];
    if (tid == 0) { s_ntop = 0u; s_ncand = 0u; }
    __syncthreads();

    // two-level suffix-scan bucket find (wave 0)
    if (tid < 64) {
        int l = tid;
        unsigned c = 0;
        for (int j = 0; j < 64; ++j) c += lhist[l * 64 + j];
        unsigned x = c;
        #pragma unroll
        for (int d = 1; d < 64; d <<= 1) {
            unsigned t = __shfl_down(x, d, 64);
            x += (l + d < 64) ? t : 0u;
        }
        unsigned long long m = __ballot(x >= KTOP);
        int L = 63 - __builtin_clzll(m);
        unsigned above = (L < 63) ? __shfl(x, L + 1, 64) : 0u;
        unsigned r1 = KTOP - above;
        unsigned y = lhist[L * 64 + l];
        #pragma unroll
        for (int d = 1; d < 64; d <<= 1) {
            unsigned t = __shfl_down(y, d, 64);
            y += (l + d < 64) ? t : 0u;
        }
        unsigned long long m2 = __ballot(y >= r1);
        int L2 = 63 - __builtin_clzll(m2);
        unsigned above2 = (L2 < 63) ? __shfl(y, L2 + 1, 64) : 0u;
        if (l == 0) { s_bucket = (unsigned)(L * 64 + L2); s_rank = r1 - above2; }
    }
    __syncthreads();
    unsigned bucket = s_bucket;

    // scan alpha: above-bucket -> LDS top list; in-bucket -> global candidates
    const float4* a4 = (const float4*)alpha;
    for (int i = tid; i < T_LEN / 16; i += 256) {
        float4 v0 = a4[4 * i], v1 = a4[4 * i + 1], v2 = a4[4 * i + 2], v3 = a4[4 * i + 3];
        float vals[16] = {v0.x, v0.y, v0.z, v0.w, v1.x, v1.y, v1.z, v1.w,
                          v2.x, v2.y, v2.z, v2.w, v3.x, v3.y, v3.z, v3.w};
        #pragma unroll
        for (int c = 0; c < 16; ++c) {
            unsigned key = monokey(vals[c]);
            unsigned kb  = key >> 20;
            if (kb > bucket) {
                unsigned p = atomicAdd(&s_ntop, 1u);
                if (p < 96) { s_sidx[p] = i * 16 + c; s_val[p] = vals[c]; }
            } else if (kb == bucket) {
                unsigned p = atomicAdd(&s_ncand, 1u);
                if (p < CAPB) { candk[p] = key; candi[p] = (unsigned)(i * 16 + c); }
            }
        }
    }
    __syncthreads();
    unsigned n = s_ncand; if (n > CAPB) n = CAPB;
    unsigned r = s_rank;

    // exact kth among in-bucket candidates (n expected ~60)
    for (unsigned i = tid; i < n; i += 256) {
        unsigned k0 = candk[i];
        unsigned gt = 0, eq = 0;
        for (unsigned j = 0; j < n; ++j) {
            unsigned kj = candk[j];
            gt += (kj > k0);
            eq += (kj == k0);
        }
        if (gt < r && r <= gt + eq) s_kth = k0;
    }
    __syncthreads();
    unsigned kth = s_kth;
    for (unsigned i = tid; i < n; i += 256) {
        unsigned k0 = candk[i];
        if (k0 >= kth) {
            unsigned p = atomicAdd(&s_ntop, 1u);
            if (p < 96) { s_sidx[p] = (int)candi[i]; s_val[p] = unmonokey(k0); }
        }
    }
    __syncthreads();

    // softmax over 64 values (wave 0)
    if (tid < KTOP) {
        float v = s_val[tid];
        float m = v;
        #pragma unroll
        for (int d = 32; d; d >>= 1) m = fmaxf(m, __shfl_xor(m, d, 64));
        float e = expf(v - m);
        float s = e;
        #pragma unroll
        for (int d = 32; d; d >>= 1) s += __shfl_xor(s, d, 64);
        s_wgt[tid] = e / s;
    }
    __syncthreads();

    // attn_h: each thread owns cols tid and tid+256
    {
        float acc0 = 0.f, acc1 = 0.f;
        for (int k = 0; k < KTOP; ++k) {
            const float* row = hs + (size_t)s_sidx[k] * HID;
            float w = s_wgt[k];
            acc0 += w * row[tid];
            acc1 += w * row[tid + 256];
        }
        s_attn[tid] = acc0;
        s_attn[tid + 256] = acc1;
    }
    __syncthreads();

    // head: logits l = wv, wv+4 (wave 0 does 0 and 4)
    for (int l = wv; l < 5; l += 4) {
        float a = 0.f;
        for (int c = lane; c < 1537; c += 64) {
            float pv = (c < 512) ? fea[c] : (c < 1024) ? s_attn[c - 512]
                      : (c < 1536) ? h[c - 1024] : 64.0f;
            a += pv * Wout[l * 1537 + c];
        }
        #pragma unroll
        for (int d = 32; d; d >>= 1) a += __shfl_xor(a, d, 64);
        if (lane == 0) s_logit[l] = a + bout[l];
    }
    __syncthreads();
    if (tid == 0) {
        float m = s_logit[0];
        for (int l = 1; l < 5; ++l) m = fmaxf(m, s_logit[l]);
        float s = 0.f;
        for (int l = 0; l < 5; ++l) s += expf(s_logit[l] - m);
        float lse = m + logf(s);
        for (int l = 0; l < 5; ++l) out[l] = s_logit[l] - lse;
    }
}

extern "C" void kernel_launch(void* const* d_in, const int* in_sizes, int n_in,
                              void* d_out, int out_size, void* d_ws, size_t ws_size,
                              hipStream_t stream) {
    const float* fea  = (const float*)d_in[0];
    const float* h    = (const float*)d_in[1];
    const float* fs   = (const float*)d_in[2];
    const float* hs   = (const float*)d_in[3];
    const float* w_ih = (const float*)d_in[4];
    const float* w_hh = (const float*)d_in[5];
    const float* b_ih = (const float*)d_in[6];
    const float* b_hh = (const float*)d_in[7];
    const float* Wout = (const float*)d_in[8];
    const float* bout = (const float*)d_in[9];
    float* out = (float*)d_out;

    unsigned char* w = (unsigned char*)d_ws;
    float*    alpha   = (float*)   (w + OFF_ALPHA);
    unsigned* ghist   = (unsigned*)(w + OFF_HIST);
    unsigned* counter = (unsigned*)(w + OFF_CNT);
    unsigned* candk   = (unsigned*)(w + OFF_CANDK);
    unsigned* candi   = (unsigned*)(w + OFF_CANDI);

    hipMemsetAsync(ghist, 0, NBIN * sizeof(unsigned) + 16, stream);  // hist + counter
    k_all<<<GRID, 256, 0, stream>>>(fs, fea, h, hs, w_ih, w_hh, b_ih, b_hh,
                                    Wout, bout, alpha, ghist, counter,
                                    candk, candi, out);
}

// Round 6
// 138.074 us; speedup vs baseline: 2.4805x; 2.4805x over previous
//
#include <hip/hip_runtime.h>
#include <math.h>

#define T_LEN 200000
#define DIM   512
#define HID   512
#define KTOP  64
#define NBIN  4096
#define CAPB  4096
#define GRID  2048
#define NB_GRU 64
#define NB_ALPHA (GRID - NB_GRU)       // 1984
#define RPB   101                      // rows per alpha block (1984*101 >= 200000)

// workspace layout (bytes)
#define OFF_ALPHA 0u            // 800000
#define OFF_HIST  800000u       // NBIN*4 = 16384
#define OFF_CNT   816384u       // 8 u32 (zeroed with hist)
#define OFF_CANDK 816416u       // CAPB*4
#define OFF_CANDI 832800u       // CAPB*4
#define OFF_TOPK  849184u       // 128 u32
#define OFF_TOPI  849696u       // 128 u32

__device__ __forceinline__ unsigned monokey(float f) {
    unsigned u = __float_as_uint(f);
    return (u & 0x80000000u) ? ~u : (u | 0x80000000u);
}
__device__ __forceinline__ float unmonokey(unsigned k) {
    return __uint_as_float((k & 0x80000000u) ? (k & 0x7fffffffu) : ~k);
}
__device__ __forceinline__ float dot8(float4 a0, float4 a1, float4 f0, float4 f1) {
    return a0.x*f0.x + a0.y*f0.y + a0.z*f0.z + a0.w*f0.w
         + a1.x*f1.x + a1.y*f1.y + a1.z*f1.z + a1.w*f1.w;
}

// bucket+rank from a 4096-bin histogram in LDS; wave-0 only. Returns via refs.
__device__ __forceinline__ void find_bucket(const unsigned* s_h, int l,
                                            unsigned* s_bucket, unsigned* s_rank) {
    unsigned c = 0;
    for (int j = 0; j < 64; ++j) c += s_h[l * 64 + j];
    unsigned x = c;
    #pragma unroll
    for (int d = 1; d < 64; d <<= 1) {
        unsigned t = __shfl_down(x, d, 64);
        x += (l + d < 64) ? t : 0u;
    }
    unsigned long long m = __ballot(x >= KTOP);
    int L = 63 - __builtin_clzll(m);
    unsigned above = (L < 63) ? __shfl(x, L + 1, 64) : 0u;
    unsigned r1 = KTOP - above;
    unsigned y = s_h[L * 64 + l];
    #pragma unroll
    for (int d = 1; d < 64; d <<= 1) {
        unsigned t = __shfl_down(y, d, 64);
        y += (l + d < 64) ? t : 0u;
    }
    unsigned long long m2 = __ballot(y >= r1);
    int L2 = 63 - __builtin_clzll(m2);
    unsigned above2 = (L2 < 63) ? __shfl(y, L2 + 1, 64) : 0u;
    if (l == 0) { *s_bucket = (unsigned)(L * 64 + L2); *s_rank = r1 - above2; }
}

// ---- K1: blocks 0..63 GRU; blocks 64..2047 alpha (contiguous chunks) ----
__global__ void k_main(const float* __restrict__ fs, const float* __restrict__ fea,
                       const float* __restrict__ h,
                       const float* __restrict__ w_ih, const float* __restrict__ w_hh,
                       const float* __restrict__ b_ih, const float* __restrict__ b_hh,
                       float* __restrict__ alpha, unsigned* __restrict__ ghist,
                       float* __restrict__ out) {
    int tid = threadIdx.x;             // 256
    int b   = blockIdx.x;

    if (b < NB_GRU) {
        int tx = tid & 31, ty = tid >> 5;
        int j  = b * 8 + ty;
        const float4* f4  = (const float4*)fea;
        const float4* h4  = (const float4*)h;
        const float4* wi4 = (const float4*)w_ih;
        const float4* wh4 = (const float4*)w_hh;
        int r0 = j, r1 = HID + j, r2 = 2 * HID + j;
        float gir = 0, giz = 0, gin = 0, ghr = 0, ghz = 0, ghn = 0;
        #pragma unroll
        for (int it = 0; it < 4; ++it) {
            int c = tx + it * 32;
            float4 x = f4[c], hh = h4[c];
            float4 w;
            w = wi4[(size_t)r0 * 128 + c]; gir += w.x*x.x + w.y*x.y + w.z*x.z + w.w*x.w;
            w = wi4[(size_t)r1 * 128 + c]; giz += w.x*x.x + w.y*x.y + w.z*x.z + w.w*x.w;
            w = wi4[(size_t)r2 * 128 + c]; gin += w.x*x.x + w.y*x.y + w.z*x.z + w.w*x.w;
            w = wh4[(size_t)r0 * 128 + c]; ghr += w.x*hh.x + w.y*hh.y + w.z*hh.z + w.w*hh.w;
            w = wh4[(size_t)r1 * 128 + c]; ghz += w.x*hh.x + w.y*hh.y + w.z*hh.z + w.w*hh.w;
            w = wh4[(size_t)r2 * 128 + c]; ghn += w.x*hh.x + w.y*hh.y + w.z*hh.z + w.w*hh.w;
        }
        #pragma unroll
        for (int d = 16; d; d >>= 1) {
            gir += __shfl_xor(gir, d, 64);
            giz += __shfl_xor(giz, d, 64);
            gin += __shfl_xor(gin, d, 64);
            ghr += __shfl_xor(ghr, d, 64);
            ghz += __shfl_xor(ghz, d, 64);
            ghn += __shfl_xor(ghn, d, 64);
        }
        if (tx == 0) {
            float r = 1.f / (1.f + expf(-(gir + b_ih[r0] + ghr + b_hh[r0])));
            float z = 1.f / (1.f + expf(-(giz + b_ih[r1] + ghz + b_hh[r1])));
            float n = tanhf(gin + b_ih[r2] + r * (ghn + b_hh[r2]));
            out[5 + j] = (1.f - z) * n + z * h[j];
        }
        return;
    }

    __shared__ unsigned lhist[NBIN];   // 16 KB
    #pragma unroll
    for (int i = 0; i < NBIN / 256; ++i) lhist[tid + i * 256] = 0u;
    __syncthreads();

    int lane = tid & 63;
    int wv   = tid >> 6;
    int ab   = b - NB_GRU;
    int start = ab * RPB;
    int end   = start + RPB; if (end > T_LEN) end = T_LEN;
    const float4* fs4  = (const float4*)fs;
    const float4* fea4 = (const float4*)fea;
    float4 f0 = fea4[lane];
    float4 f1 = fea4[64 + lane];

    int r = start + wv;
    bool v0 = r < end, v1 = (r + 4) < end;
    float4 a0 = {0,0,0,0}, a1 = a0, b0 = a0, b1 = a0;
    if (v0) { const float4* p = fs4 + (size_t)r * 128;       a0 = p[lane]; a1 = p[64 + lane]; }
    if (v1) { const float4* p = fs4 + (size_t)(r + 4) * 128; b0 = p[lane]; b1 = p[64 + lane]; }
    while (v0) {
        int rn = r + 8;
        bool nv0 = rn < end, nv1 = (rn + 4) < end;
        float4 na0 = {0,0,0,0}, na1 = na0, nb0 = na0, nb1 = na0;
        if (nv0) { const float4* p = fs4 + (size_t)rn * 128;       na0 = p[lane]; na1 = p[64 + lane]; }
        if (nv1) { const float4* p = fs4 + (size_t)(rn + 4) * 128; nb0 = p[lane]; nb1 = p[64 + lane]; }
        float s0 = dot8(a0, a1, f0, f1);
        float s1 = dot8(b0, b1, f0, f1);
        #pragma unroll
        for (int m = 32; m; m >>= 1) {
            s0 += __shfl_xor(s0, m, 64);
            s1 += __shfl_xor(s1, m, 64);
        }
        if (lane == 0) {
            alpha[r] = s0; atomicAdd(&lhist[monokey(s0) >> 20], 1u);
            if (v1) { alpha[r + 4] = s1; atomicAdd(&lhist[monokey(s1) >> 20], 1u); }
        }
        a0 = na0; a1 = na1; b0 = nb0; b1 = nb1;
        v0 = nv0; v1 = nv1; r = rn;
    }
    __syncthreads();
    #pragma unroll
    for (int i = 0; i < NBIN / 256; ++i) {
        unsigned c = lhist[tid + i * 256];
        if (c) atomicAdd(&ghist[tid + i * 256], c);
    }
}

// ---- K2: parallel scan — tops and in-bucket candidates to global lists ----
__global__ void k_scan(const float* __restrict__ alpha, const unsigned* __restrict__ ghist,
                       unsigned* __restrict__ gcnt,
                       unsigned* __restrict__ candk, unsigned* __restrict__ candi,
                       unsigned* __restrict__ topk, unsigned* __restrict__ topi) {
    __shared__ unsigned s_h[NBIN];
    __shared__ unsigned s_bucket, s_rank;
    int tid = threadIdx.x;             // 256
    for (int i = tid; i < NBIN; i += 256) s_h[i] = ghist[i];
    __syncthreads();
    if (tid < 64) find_bucket(s_h, tid, &s_bucket, &s_rank);
    __syncthreads();
    unsigned bucket = s_bucket;

    int i = blockIdx.x * 256 + tid;    // one float4 per thread
    if (i < T_LEN / 4) {
        float4 v = ((const float4*)alpha)[i];
        float vv[4] = {v.x, v.y, v.z, v.w};
        #pragma unroll
        for (int c = 0; c < 4; ++c) {
            unsigned key = monokey(vv[c]);
            unsigned kb  = key >> 20;
            if (kb > bucket) {
                unsigned p = atomicAdd(&gcnt[1], 1u);
                if (p < 128) { topk[p] = key; topi[p] = (unsigned)(i * 4 + c); }
            } else if (kb == bucket) {
                unsigned p = atomicAdd(&gcnt[0], 1u);
                if (p < CAPB) { candk[p] = key; candi[p] = (unsigned)(i * 4 + c); }
            }
        }
    }
}

// ---- K3: kth + top-64 + softmax + attn + head (1 block, 256 thr) ----
__global__ void k_final(const unsigned* __restrict__ ghist, const unsigned* __restrict__ gcnt,
                        const unsigned* __restrict__ candk, const unsigned* __restrict__ candi,
                        const unsigned* __restrict__ topk, const unsigned* __restrict__ topi,
                        const float* __restrict__ hs, const float* __restrict__ fea,
                        const float* __restrict__ h, const float* __restrict__ Wout,
                        const float* __restrict__ bout, float* __restrict__ out) {
    __shared__ unsigned s_h[NBIN];     // 16 KB
    __shared__ unsigned s_bucket, s_rank, s_kth, s_ntop;
    __shared__ float    s_val[96];
    __shared__ int      s_sidx[96];
    __shared__ float    s_wgt[KTOP];
    __shared__ float    s_part[4][HID];
    __shared__ float    s_attn[HID];
    __shared__ float    s_logit[8];
    int tid = threadIdx.x;             // 256
    int lane = tid & 63, wv = tid >> 6;

    for (int i = tid; i < NBIN; i += 256) s_h[i] = ghist[i];
    __syncthreads();
    if (tid < 64) find_bucket(s_h, tid, &s_bucket, &s_rank);
    __syncthreads();
    unsigned n = gcnt[0]; if (n > CAPB) n = CAPB;
    unsigned ntop0 = gcnt[1]; if (ntop0 > 96) ntop0 = 96;
    unsigned r = s_rank;

    // exact kth among in-bucket candidates (expected n ~ 60)
    for (unsigned i = tid; i < n; i += 256) {
        unsigned k0 = candk[i];
        unsigned gt = 0, eq = 0;
        for (unsigned j = 0; j < n; ++j) {
            unsigned kj = candk[j];
            gt += (kj > k0);
            eq += (kj == k0);
        }
        if (gt < r && r <= gt + eq) s_kth = k0;
    }
    for (unsigned i = tid; i < ntop0; i += 256) {
        s_val[i]  = unmonokey(topk[i]);
        s_sidx[i] = (int)topi[i];
    }
    if (tid == 0) s_ntop = ntop0;
    __syncthreads();
    unsigned kth = s_kth;
    for (unsigned i = tid; i < n; i += 256) {
        unsigned k0 = candk[i];
        if (k0 >= kth) {
            unsigned p = atomicAdd(&s_ntop, 1u);
            if (p < 96) { s_sidx[p] = (int)candi[i]; s_val[p] = unmonokey(k0); }
        }
    }
    __syncthreads();

    // softmax over 64 values (wave 0)
    if (tid < KTOP) {
        float v = s_val[tid];
        float m = v;
        #pragma unroll
        for (int d = 32; d; d >>= 1) m = fmaxf(m, __shfl_xor(m, d, 64));
        float e = expf(v - m);
        float s = e;
        #pragma unroll
        for (int d = 32; d; d >>= 1) s += __shfl_xor(s, d, 64);
        s_wgt[tid] = e / s;
    }
    __syncthreads();

    // attn: wave wv accumulates 16 weighted rows, coalesced float4
    {
        float4 acc0 = {0,0,0,0}, acc1 = {0,0,0,0};
        for (int kk = wv * 16; kk < wv * 16 + 16; ++kk) {
            const float4* row4 = (const float4*)(hs + (size_t)s_sidx[kk] * HID);
            float w = s_wgt[kk];
            float4 x = row4[lane], y = row4[64 + lane];
            acc0.x += w * x.x; acc0.y += w * x.y; acc0.z += w * x.z; acc0.w += w * x.w;
            acc1.x += w * y.x; acc1.y += w * y.y; acc1.z += w * y.z; acc1.w += w * y.w;
        }
        ((float4*)s_part[wv])[lane]      = acc0;
        ((float4*)s_part[wv])[64 + lane] = acc1;
    }
    __syncthreads();
    for (int c = tid; c < HID; c += 256)
        s_attn[c] = s_part[0][c] + s_part[1][c] + s_part[2][c] + s_part[3][c];
    __syncthreads();

    // head: 5 logits over concat(fea, attn, h, 64.0) + log_softmax
    for (int l = wv; l < 5; l += 4) {
        float a = 0.f;
        for (int c = lane; c < 1537; c += 64) {
            float pv = (c < 512) ? fea[c] : (c < 1024) ? s_attn[c - 512]
                      : (c < 1536) ? h[c - 1024] : 64.0f;
            a += pv * Wout[l * 1537 + c];
        }
        #pragma unroll
        for (int d = 32; d; d >>= 1) a += __shfl_xor(a, d, 64);
        if (lane == 0) s_logit[l] = a + bout[l];
    }
    __syncthreads();
    if (tid == 0) {
        float m = s_logit[0];
        for (int l = 1; l < 5; ++l) m = fmaxf(m, s_logit[l]);
        float s = 0.f;
        for (int l = 0; l < 5; ++l) s += expf(s_logit[l] - m);
        float lse = m + logf(s);
        for (int l = 0; l < 5; ++l) out[l] = s_logit[l] - lse;
    }
}

extern "C" void kernel_launch(void* const* d_in, const int* in_sizes, int n_in,
                              void* d_out, int out_size, void* d_ws, size_t ws_size,
                              hipStream_t stream) {
    const float* fea  = (const float*)d_in[0];
    const float* h    = (const float*)d_in[1];
    const float* fs   = (const float*)d_in[2];
    const float* hs   = (const float*)d_in[3];
    const float* w_ih = (const float*)d_in[4];
    const float* w_hh = (const float*)d_in[5];
    const float* b_ih = (const float*)d_in[6];
    const float* b_hh = (const float*)d_in[7];
    const float* Wout = (const float*)d_in[8];
    const float* bout = (const float*)d_in[9];
    float* out = (float*)d_out;

    unsigned char* w = (unsigned char*)d_ws;
    float*    alpha = (float*)   (w + OFF_ALPHA);
    unsigned* ghist = (unsigned*)(w + OFF_HIST);
    unsigned* gcnt  = (unsigned*)(w + OFF_CNT);
    unsigned* candk = (unsigned*)(w + OFF_CANDK);
    unsigned* candi = (unsigned*)(w + OFF_CANDI);
    unsigned* topk  = (unsigned*)(w + OFF_TOPK);
    unsigned* topi  = (unsigned*)(w + OFF_TOPI);

    hipMemsetAsync(ghist, 0, NBIN * sizeof(unsigned) + 32, stream);   // hist + counters
    k_main <<<GRID, 256, 0, stream>>>(fs, fea, h, w_ih, w_hh, b_ih, b_hh, alpha, ghist, out);
    k_scan <<<(T_LEN / 4 + 255) / 256, 256, 0, stream>>>(alpha, ghist, gcnt, candk, candi, topk, topi);
    k_final<<<1, 256, 0, stream>>>(ghist, gcnt, candk, candi, topk, topi,
                                   hs, fea, h, Wout, bout, out);
}